// Round 7
// baseline (21.995 us; speedup 1.0000x reference)
//
#include <hip/hip_runtime.h>
#include <math.h>

#define NB    4
#define NPTS  4096
#define BN    (NB * NPTS)
#define TPB   512                 // 8 waves
#define QPB   64                  // queries per block
#define NBLK  (BN / QPB)          // 256 blocks -> 1 per CU
#define G     64                  // j-groups per block
#define JG    (NPTS / G)          // 64 j per group
#define IT    8                   // queries per thread
#define QCOLS (QPB / IT)          // 8 query-columns
#define NW    (TPB / 64)          // 8 waves
#define PADIDX(i) ((i) + ((i) >> 6))   // +1 float4 pad per 64 entries

__device__ inline float wave_sum(float v) {
#pragma unroll
    for (int o = 32; o > 0; o >>= 1) v += __shfl_xor(v, o);
    return v;
}

// One block = 64 queries of one batch vs ALL 4096 points (staged in LDS).
// t = g_local*8 + qcol within a wave; wave w owns groups [8w, 8w+8).
// Group stride 65 float4: the 8 broadcast groups of a wave cover all 32 banks.
// Last-arriving block (atomicInc wrap trick, no init needed) does the final 3KB reduce.
__global__ __launch_bounds__(TPB) void fused_kernel(const float* __restrict__ pc,
                                                    float* __restrict__ bpart,
                                                    unsigned int* __restrict__ cnt,
                                                    float* __restrict__ out) {
    __shared__ float4 lpt[NPTS + G];
    __shared__ float  smin[NW][QPB];
    __shared__ float  scen[NW][3];
    __shared__ float  svar[NB], ses[NB];
    __shared__ unsigned int s_old;

    int b    = blockIdx.x >> 6;        // batch (64 blocks per batch)
    int blkq = blockIdx.x & 63;        // query-block within batch
    int iq0  = blkq * QPB;
    const float* p = pc + (size_t)b * NPTS * 3;
    int t = threadIdx.x;
    int lane = t & 63, w = t >> 6;

    // ---- stage batch: (x,y,z,|x|^2), padded ----
    for (int i = t; i < NPTS; i += TPB) {
        float x = p[3*i+0], y = p[3*i+1], z = p[3*i+2];
        lpt[PADIDX(i)] = make_float4(x, y, z, fmaf(x, x, fmaf(y, y, z * z)));
    }
    __syncthreads();

    // ---- centroid partials (same order in every block of a batch) ----
    float sx = 0.f, sy = 0.f, sz = 0.f;
    for (int i = t; i < NPTS; i += TPB) {
        float4 q = lpt[PADIDX(i)];
        sx += q.x; sy += q.y; sz += q.z;
    }
    sx = wave_sum(sx); sy = wave_sum(sy); sz = wave_sum(sz);
    if (lane == 0) { scen[w][0] = sx; scen[w][1] = sy; scen[w][2] = sz; }

    // ---- per-thread: 8 queries (prefolded -2x) vs group g's 64 points ----
    int qcol = t & (QCOLS - 1);
    int g    = t >> 3;                 // global group index 0..63
    float ax[IT], ay[IT], az[IT], m[IT];
#pragma unroll
    for (int k = 0; k < IT; ++k) {
        int iq = iq0 + qcol * IT + k;
        float4 q = lpt[PADIDX(iq)];
        ax[k] = -2.f * q.x; ay[k] = -2.f * q.y; az[k] = -2.f * q.z;
        m[k] = 1e30f;
    }
    const float4* gp = &lpt[g * (JG + 1)];

    int gd = blkq;                     // group containing this block's queries (JG==QPB)
    int wd = gd >> 3;                  // wave owning that group
    if (w == wd) {                     // wave-uniform diagonal branch
        int idl[IT];
#pragma unroll
        for (int k = 0; k < IT; ++k)
            idl[k] = (g == gd) ? (qcol * IT + k) : -1;
#pragma unroll 4
        for (int j = 0; j < JG; ++j) {
            float4 q = gp[j];
#pragma unroll
            for (int k = 0; k < IT; ++k) {
                float e = fmaf(ax[k], q.x, fmaf(ay[k], q.y, fmaf(az[k], q.z, q.w)));
                m[k] = fminf(m[k], (j == idl[k]) ? 1e30f : e);
            }
        }
    } else {
#pragma unroll 8
        for (int j = 0; j < JG; j += 2) {      // paired -> v_min3
            float4 q0 = gp[j], q1 = gp[j+1];
#pragma unroll
            for (int k = 0; k < IT; ++k) {
                float e0 = fmaf(ax[k], q0.x, fmaf(ay[k], q0.y, fmaf(az[k], q0.z, q0.w)));
                float e1 = fmaf(ax[k], q1.x, fmaf(ay[k], q1.y, fmaf(az[k], q1.z, q1.w)));
                m[k] = fminf(fminf(m[k], e0), e1);
            }
        }
    }

    // ---- min across the wave's 8 groups (g_local = lane bits 3..5) ----
#pragma unroll
    for (int k = 0; k < IT; ++k) {
        m[k] = fminf(m[k], __shfl_xor(m[k], 8));
        m[k] = fminf(m[k], __shfl_xor(m[k], 16));
        m[k] = fminf(m[k], __shfl_xor(m[k], 32));
    }
    if (lane < QCOLS) {
#pragma unroll
        for (int k = 0; k < IT; ++k) smin[w][qcol * IT + k] = m[k];
    }
    __syncthreads();

    // ---- wave 0: min across 8 waves, exp, variance terms, block partials ----
    if (t < QPB) {
        float cx = 0.f, cy = 0.f, cz = 0.f;
#pragma unroll
        for (int ww = 0; ww < NW; ++ww) {
            cx += scen[ww][0]; cy += scen[ww][1]; cz += scen[ww][2];
        }
        cx *= (1.f / NPTS); cy *= (1.f / NPTS); cz *= (1.f / NPTS);

        float mm = smin[0][t];
#pragma unroll
        for (int ww = 1; ww < NW; ++ww) mm = fminf(mm, smin[ww][t]);

        int iq = iq0 + t;
        float4 q = lpt[PADIDX(iq)];
        float es = __expf(-5.f * fmaxf(q.w + mm, 0.f));

        float dx = q.x - cx, dy = q.y - cy, dz = q.z - cz;
        float d2 = fmaf(dx, dx, fmaf(dy, dy, dz * dz));
        float s1 = sqrtf(d2);

        es = wave_sum(es);
        float S1 = wave_sum(s1);
        float S2 = wave_sum(d2);
        if (t == 0) {
            bpart[blockIdx.x * 3 + 0] = S1;
            bpart[blockIdx.x * 3 + 1] = S2;
            bpart[blockIdx.x * 3 + 2] = es;
            __threadfence();                       // release bpart store
            // wrap-increment: exactly one block per call observes NBLK-2,
            // for ANY initial counter value (poison-proof, no init/reset).
            s_old = atomicInc(cnt, NBLK - 1u);
        }
    }
    __syncthreads();
    if (s_old != NBLK - 2u) return;

    // ---- last-arriving block: reduce 256x3 partials, write scalar ----
    __threadfence();                               // acquire
    if (t < NBLK) {
        float s1 = bpart[t*3+0], s2 = bpart[t*3+1], e = bpart[t*3+2];
        s1 = wave_sum(s1); s2 = wave_sum(s2); e = wave_sum(e);
        if ((t & 63) == 0) {                       // wave w == batch w
            int bb = t >> 6;
            svar[bb] = (s2 - s1 * s1 * (1.f / NPTS)) * (1.f / (NPTS - 1));
            ses[bb]  = e;
        }
    }
    __syncthreads();
    if (t == 0) {
        float vs = 0.f, et = 0.f;
#pragma unroll
        for (int bb = 0; bb < NB; ++bb) { vs += svar[bb]; et += ses[bb]; }
        out[0] = vs * (1.f / NB) + et * (1.f / BN);
    }
}

extern "C" void kernel_launch(void* const* d_in, const int* in_sizes, int n_in,
                              void* d_out, int out_size, void* d_ws, size_t ws_size,
                              hipStream_t stream) {
    const float* pc = (const float*)d_in[0];
    float* out = (float*)d_out;
    unsigned int* cnt = (unsigned int*)d_ws;           // self-healing, no init
    float* bpart = (float*)((char*)d_ws + 256);        // NBLK*3 floats = 3 KB

    fused_kernel<<<NBLK, TPB, 0, stream>>>(pc, bpart, cnt, out);
}

// Round 8
// 20.344 us; speedup vs baseline: 1.0811x; 1.0811x over previous
//
#include <hip/hip_runtime.h>
#include <math.h>

#define NB    4
#define NPTS  4096
#define BN    (NB * NPTS)
#define TPB   512                 // 8 waves
#define QPB   64                  // queries per block
#define NBLK  (BN / QPB)          // 256 blocks -> 1 per CU
#define G     32                  // j-groups per block
#define JG    (NPTS / G)          // 128 j per group
#define IT    4                   // queries per thread
#define QCOLS (QPB / IT)          // 16 query-columns
#define NW    (TPB / 64)          // 8 waves
#define PADIDX(i) ((i) + ((i) >> 7))   // +1 float4 pad per 128 entries

__device__ inline float wave_sum(float v) {
#pragma unroll
    for (int o = 32; o > 0; o >>= 1) v += __shfl_xor(v, o);
    return v;
}

// One block = 64 queries of one batch vs ALL 4096 points (staged in LDS).
// t = g_local*16 + qcol; wave w owns groups [4w, 4w+4).
// Group stride 129 float4 -> per-group bank offset 4: conflict-free broadcasts.
// Last-arriving block (atomicInc wrap trick, poison-proof) does the 3KB finale.
__global__ __launch_bounds__(TPB) void fused_kernel(const float* __restrict__ pc,
                                                    float* __restrict__ bpart,
                                                    unsigned int* __restrict__ cnt,
                                                    float* __restrict__ out) {
    __shared__ float4 lpt[NPTS + G];
    __shared__ float  smin[NW][QPB];
    __shared__ float  scen[NW][3];
    __shared__ float  svar[NB], ses[NB];
    __shared__ unsigned int s_old;

    int b    = blockIdx.x >> 6;        // batch (64 blocks per batch)
    int blkq = blockIdx.x & 63;        // query-block within batch
    int iq0  = blkq * QPB;
    const float* p = pc + (size_t)b * NPTS * 3;
    int t = threadIdx.x;
    int lane = t & 63, w = t >> 6;

    // ---- stage batch (x,y,z,|x|^2) + centroid partials from the same regs ----
    float sx = 0.f, sy = 0.f, sz = 0.f;
    for (int i = t; i < NPTS; i += TPB) {
        float x = p[3*i+0], y = p[3*i+1], z = p[3*i+2];
        lpt[PADIDX(i)] = make_float4(x, y, z, fmaf(x, x, fmaf(y, y, z * z)));
        sx += x; sy += y; sz += z;
    }
    sx = wave_sum(sx); sy = wave_sum(sy); sz = wave_sum(sz);
    if (lane == 0) { scen[w][0] = sx; scen[w][1] = sy; scen[w][2] = sz; }
    __syncthreads();

    // ---- per-thread: 4 queries (prefolded -2x) vs group g's 128 points ----
    int qcol = t & (QCOLS - 1);
    int g    = t >> 4;                 // global group index 0..31
    float ax[IT], ay[IT], az[IT], m[IT];
#pragma unroll
    for (int k = 0; k < IT; ++k) {
        int iq = iq0 + qcol * IT + k;
        float4 q = lpt[PADIDX(iq)];
        ax[k] = -2.f * q.x; ay[k] = -2.f * q.y; az[k] = -2.f * q.z;
        m[k] = 1e30f;
    }
    const float4* gp = &lpt[g * (JG + 1)];

    int gd = blkq >> 1;                // group containing this block's queries
    int wd = blkq >> 3;                // wave owning that group
    if (w == wd) {                     // wave-uniform diagonal branch
        int idl[IT];
#pragma unroll
        for (int k = 0; k < IT; ++k)
            idl[k] = (g == gd) ? (iq0 + qcol * IT + k - gd * JG) : -1;
#pragma unroll 4
        for (int j = 0; j < JG; ++j) {
            float4 q = gp[j];
#pragma unroll
            for (int k = 0; k < IT; ++k) {
                float e = fmaf(ax[k], q.x, fmaf(ay[k], q.y, fmaf(az[k], q.z, q.w)));
                m[k] = fminf(m[k], (j == idl[k]) ? 1e30f : e);
            }
        }
    } else {
#pragma unroll 8
        for (int j = 0; j < JG; j += 2) {      // paired -> v_min3
            float4 q0 = gp[j], q1 = gp[j+1];
#pragma unroll
            for (int k = 0; k < IT; ++k) {
                float e0 = fmaf(ax[k], q0.x, fmaf(ay[k], q0.y, fmaf(az[k], q0.z, q0.w)));
                float e1 = fmaf(ax[k], q1.x, fmaf(ay[k], q1.y, fmaf(az[k], q1.z, q1.w)));
                m[k] = fminf(fminf(m[k], e0), e1);
            }
        }
    }

    // ---- min across the wave's 4 groups (xor 16, 32) ----
#pragma unroll
    for (int k = 0; k < IT; ++k) {
        m[k] = fminf(m[k], __shfl_xor(m[k], 16));
        m[k] = fminf(m[k], __shfl_xor(m[k], 32));
    }
    if (lane < QCOLS) {
#pragma unroll
        for (int k = 0; k < IT; ++k) smin[w][qcol * IT + k] = m[k];
    }
    __syncthreads();

    // ---- wave 0: min across 8 waves, exp, variance terms, block partials ----
    if (t < QPB) {
        float cx = 0.f, cy = 0.f, cz = 0.f;
#pragma unroll
        for (int ww = 0; ww < NW; ++ww) {
            cx += scen[ww][0]; cy += scen[ww][1]; cz += scen[ww][2];
        }
        cx *= (1.f / NPTS); cy *= (1.f / NPTS); cz *= (1.f / NPTS);

        float mm = smin[0][t];
#pragma unroll
        for (int ww = 1; ww < NW; ++ww) mm = fminf(mm, smin[ww][t]);

        int iq = iq0 + t;
        float4 q = lpt[PADIDX(iq)];
        float es = __expf(-5.f * fmaxf(q.w + mm, 0.f));   // clamp commutes with min

        float dx = q.x - cx, dy = q.y - cy, dz = q.z - cz;
        float d2 = fmaf(dx, dx, fmaf(dy, dy, dz * dz));
        float s1 = sqrtf(d2);

        es = wave_sum(es);
        float S1 = wave_sum(s1);
        float S2 = wave_sum(d2);
        if (t == 0) {
            bpart[blockIdx.x * 3 + 0] = S1;
            bpart[blockIdx.x * 3 + 1] = S2;
            bpart[blockIdx.x * 3 + 2] = es;
            __threadfence();                       // release bpart store
            // wrap-increment: exactly one block per call observes NBLK-2,
            // for ANY initial counter value (poison-proof, no init/reset).
            s_old = atomicInc(cnt, NBLK - 1u);
        }
    }
    __syncthreads();
    if (s_old != NBLK - 2u) return;

    // ---- last-arriving block: reduce 256x3 partials, write scalar ----
    __threadfence();                               // acquire
    if (t < NBLK) {
        float s1 = bpart[t*3+0], s2 = bpart[t*3+1], e = bpart[t*3+2];
        s1 = wave_sum(s1); s2 = wave_sum(s2); e = wave_sum(e);
        if ((t & 63) == 0) {                       // wave w == batch w
            int bb = t >> 6;
            svar[bb] = (s2 - s1 * s1 * (1.f / NPTS)) * (1.f / (NPTS - 1));
            ses[bb]  = e;
        }
    }
    __syncthreads();
    if (t == 0) {
        float vs = 0.f, et = 0.f;
#pragma unroll
        for (int bb = 0; bb < NB; ++bb) { vs += svar[bb]; et += ses[bb]; }
        out[0] = vs * (1.f / NB) + et * (1.f / BN);
    }
}

extern "C" void kernel_launch(void* const* d_in, const int* in_sizes, int n_in,
                              void* d_out, int out_size, void* d_ws, size_t ws_size,
                              hipStream_t stream) {
    const float* pc = (const float*)d_in[0];
    float* out = (float*)d_out;
    unsigned int* cnt = (unsigned int*)d_ws;           // self-healing, no init
    float* bpart = (float*)((char*)d_ws + 256);        // NBLK*3 floats = 3 KB

    fused_kernel<<<NBLK, TPB, 0, stream>>>(pc, bpart, cnt, out);
}